// Round 1
// baseline (4619.261 us; speedup 1.0000x reference)
//
#include <hip/hip_runtime.h>
#include <hip/hip_fp16.h>

// MemoryAsContextTitan: B=4, S=3968, D=512, H=8, HD=64, CHUNK=496, NPM=32, MEM=1024, nch=8
// Sequential scan over 8 chunks; each step = GEMM chain + retrieve attn + 8-head MHA + EMA.
// All matmuls via bf16 MFMA (16x16x32), fp32 accumulate. f32 activations in ws, converted
// to bf16 during LDS staging. Weights pre-transposed+converted to bf16 once per call.

typedef __attribute__((ext_vector_type(8))) short short8;
typedef __attribute__((ext_vector_type(4))) float f32x4;

static __device__ __forceinline__ unsigned short f32_bf16(float f) {
  unsigned int u = __float_as_uint(f);
  u += 0x7FFFu + ((u >> 16) & 1u);            // RNE
  return (unsigned short)(u >> 16);
}

// ---------------------------------------------------------------------------
// GEMM: C[z][m][n] = scale * sum_k A[z][m][k] * Bt[z][n][k]  (+ bias[n])
// A rows: base + (z/H)*Asb + (z%H)*Ash + m*Ars ; Bt rows likewise (K-major).
// ATY/BTY: 0 = f32 (convert to bf16 in staging), 1 = bf16 passthrough.
// CTY: 0 = f32, 1 = fp16. GUARD: guard rows >= M (per-z). Strides in elements.
// ---------------------------------------------------------------------------
template<int BM, int BN, int ATY, int BTY, int CTY, bool GUARD, bool BIAS>
__global__ __launch_bounds__(256) void gemm_abt(
    const void* __restrict__ Ap, long long Asb, long long Ash, int Ars,
    const void* __restrict__ Bp, long long Bsb, long long Bsh, int Brs,
    void* __restrict__ Cp, long long Csb, long long Csh, int Crs,
    const float* __restrict__ bias, float scale, int M, int Kdim, int H)
{
  constexpr int LDP = 40;                      // 32 + 8 pad (bank-conflict break)
  constexpr int WN = (BN >= 128) ? 2 : 1;
  constexpr int WM = 4 / WN;
  constexpr int MI = BM / (WM * 16);
  constexpr int NI = BN / (WN * 16);

  __shared__ unsigned short As[BM][LDP];
  __shared__ unsigned short Bs[BN][LDP];

  const int tid  = threadIdx.x;
  const int lane = tid & 63;
  const int w    = tid >> 6;
  const int wm   = w / WN, wn = w % WN;
  const int z    = blockIdx.z;
  const int zb   = z / H, zh = z - zb * H;
  const int m0   = blockIdx.x * BM;
  const int n0   = blockIdx.y * BN;
  const int lrow = lane & 15;
  const int lkB  = (lane >> 4) * 8;

  const float* Af = (const float*)Ap + (long long)zb * Asb + (long long)zh * Ash;
  const unsigned short* Ah = (const unsigned short*)Ap + (long long)zb * Asb + (long long)zh * Ash;
  const float* Bf = (const float*)Bp + (long long)zb * Bsb + (long long)zh * Bsh;
  const unsigned short* Bh = (const unsigned short*)Bp + (long long)zb * Bsb + (long long)zh * Bsh;
  float* Cf = (float*)Cp + (long long)zb * Csb + (long long)zh * Csh;
  unsigned short* Ch = (unsigned short*)Cp + (long long)zb * Csb + (long long)zh * Csh;

  f32x4 acc[MI][NI] = {};

  for (int k0 = 0; k0 < Kdim; k0 += 32) {
    // ---- stage A tile (BM x 32) ----
    #pragma unroll
    for (int e = tid * 8; e < BM * 32; e += 2048) {
      const int row = e >> 5, col = e & 31;
      const int grow = m0 + row;
      uint4 u = make_uint4(0u, 0u, 0u, 0u);
      if (!GUARD || grow < M) {
        if constexpr (ATY == 0) {
          const float* s = Af + (long long)grow * Ars + (k0 + col);
          const float4 f0 = *(const float4*)s;
          const float4 f1 = *(const float4*)(s + 4);
          u.x = (unsigned)f32_bf16(f0.x) | ((unsigned)f32_bf16(f0.y) << 16);
          u.y = (unsigned)f32_bf16(f0.z) | ((unsigned)f32_bf16(f0.w) << 16);
          u.z = (unsigned)f32_bf16(f1.x) | ((unsigned)f32_bf16(f1.y) << 16);
          u.w = (unsigned)f32_bf16(f1.z) | ((unsigned)f32_bf16(f1.w) << 16);
        } else {
          u = *(const uint4*)(Ah + (long long)grow * Ars + (k0 + col));
        }
      }
      *(uint4*)(&As[row][col]) = u;
    }
    // ---- stage B tile (BN x 32), no guard (N always fully valid) ----
    #pragma unroll
    for (int e = tid * 8; e < BN * 32; e += 2048) {
      const int row = e >> 5, col = e & 31;
      uint4 u = make_uint4(0u, 0u, 0u, 0u);
      if constexpr (BTY == 0) {
        const float* s = Bf + (long long)(n0 + row) * Brs + (k0 + col);
        const float4 f0 = *(const float4*)s;
        const float4 f1 = *(const float4*)(s + 4);
        u.x = (unsigned)f32_bf16(f0.x) | ((unsigned)f32_bf16(f0.y) << 16);
        u.y = (unsigned)f32_bf16(f0.z) | ((unsigned)f32_bf16(f0.w) << 16);
        u.z = (unsigned)f32_bf16(f1.x) | ((unsigned)f32_bf16(f1.y) << 16);
        u.w = (unsigned)f32_bf16(f1.z) | ((unsigned)f32_bf16(f1.w) << 16);
      } else {
        u = *(const uint4*)(Bh + (long long)(n0 + row) * Brs + (k0 + col));
      }
      *(uint4*)(&Bs[row][col]) = u;
    }
    __syncthreads();

    short8 afr[MI], bfr[NI];
    #pragma unroll
    for (int mi = 0; mi < MI; ++mi)
      afr[mi] = *(const short8*)(&As[wm * (MI * 16) + mi * 16 + lrow][lkB]);
    #pragma unroll
    for (int ni = 0; ni < NI; ++ni)
      bfr[ni] = *(const short8*)(&Bs[wn * (NI * 16) + ni * 16 + lrow][lkB]);
    #pragma unroll
    for (int mi = 0; mi < MI; ++mi)
      #pragma unroll
      for (int ni = 0; ni < NI; ++ni)
        acc[mi][ni] = __builtin_amdgcn_mfma_f32_16x16x32_bf16(afr[mi], bfr[ni], acc[mi][ni], 0, 0, 0);
    __syncthreads();
  }

  // ---- epilogue: D[row][col], row=(lane>>4)*4+r, col=lane&15 (m89-verified) ----
  #pragma unroll
  for (int ni = 0; ni < NI; ++ni) {
    const int col = n0 + wn * (NI * 16) + ni * 16 + lrow;
    const float bv = BIAS ? bias[col] : 0.0f;
    #pragma unroll
    for (int mi = 0; mi < MI; ++mi) {
      const int rbase = m0 + wm * (MI * 16) + mi * 16 + ((lane >> 4) << 2);
      #pragma unroll
      for (int r = 0; r < 4; ++r) {
        const int row = rbase + r;
        if (!GUARD || row < M) {
          const float v = acc[mi][ni][r] * scale + bv;
          if constexpr (CTY == 0) Cf[(long long)row * Crs + col] = v;
          else Ch[(long long)row * Crs + col] = __half_as_ushort(__float2half(v));
        }
      }
    }
  }
}

// ---------------------------------------------------------------------------
// Transpose + f32->bf16: out[z][c][r] = in[z][r][c]. R,C multiples of 32.
// ---------------------------------------------------------------------------
__global__ __launch_bounds__(256) void transpose_f32_bf16(
    const float* __restrict__ in, unsigned short* __restrict__ out,
    int R, int C, long long inB, long long outB)
{
  __shared__ float tile[32][33];
  const int z = blockIdx.z;
  in  += (long long)z * inB;
  out += (long long)z * outB;
  const int c0 = blockIdx.x * 32, r0 = blockIdx.y * 32;
  const int xx = threadIdx.x & 31, ys = threadIdx.x >> 5;
  #pragma unroll
  for (int yy = ys; yy < 32; yy += 8)
    tile[yy][xx] = in[(long long)(r0 + yy) * C + c0 + xx];
  __syncthreads();
  #pragma unroll
  for (int yy = ys; yy < 32; yy += 8)
    out[(long long)(c0 + yy) * R + r0 + xx] = f32_bf16(tile[xx][yy]);
}

// ---------------------------------------------------------------------------
// Row softmax, row length 1024, one wave per row (4 rows/block).
// IOTY 0: f32 in -> f32 out.  IOTY 1: fp16 in -> bf16 out (same 2-byte slots).
// ---------------------------------------------------------------------------
template<int IOTY>
__global__ __launch_bounds__(256) void softmax_rows(void* __restrict__ buf, int rowsPerZ, long long zStride)
{
  const int gr   = blockIdx.x * 4 + (threadIdx.x >> 6);
  const int lane = threadIdx.x & 63;
  const int z = gr / rowsPerZ;
  const int i = gr - z * rowsPerZ;
  float v[16];
  float* pf = nullptr;
  unsigned short* ph = nullptr;
  if constexpr (IOTY == 0) {
    pf = (float*)buf + (long long)z * zStride + (long long)i * 1024 + lane * 16;
    #pragma unroll
    for (int j = 0; j < 4; ++j) {
      const float4 f = ((const float4*)pf)[j];
      v[4*j+0] = f.x; v[4*j+1] = f.y; v[4*j+2] = f.z; v[4*j+3] = f.w;
    }
  } else {
    ph = (unsigned short*)buf + (long long)z * zStride + (long long)i * 1024 + lane * 16;
    const uint4 u0 = ((const uint4*)ph)[0];
    const uint4 u1 = ((const uint4*)ph)[1];
    const unsigned uu[8] = {u0.x, u0.y, u0.z, u0.w, u1.x, u1.y, u1.z, u1.w};
    #pragma unroll
    for (int j = 0; j < 8; ++j) {
      v[2*j]   = __half2float(__ushort_as_half((unsigned short)(uu[j] & 0xffffu)));
      v[2*j+1] = __half2float(__ushort_as_half((unsigned short)(uu[j] >> 16)));
    }
  }
  float mx = v[0];
  #pragma unroll
  for (int j = 1; j < 16; ++j) mx = fmaxf(mx, v[j]);
  #pragma unroll
  for (int d = 32; d; d >>= 1) mx = fmaxf(mx, __shfl_xor(mx, d));
  float s = 0.0f;
  #pragma unroll
  for (int j = 0; j < 16; ++j) { v[j] = __expf(v[j] - mx); s += v[j]; }
  #pragma unroll
  for (int d = 32; d; d >>= 1) s += __shfl_xor(s, d);
  const float inv = 1.0f / s;
  if constexpr (IOTY == 0) {
    #pragma unroll
    for (int j = 0; j < 4; ++j) {
      float4 f;
      f.x = v[4*j+0]*inv; f.y = v[4*j+1]*inv; f.z = v[4*j+2]*inv; f.w = v[4*j+3]*inv;
      ((float4*)pf)[j] = f;
    }
  } else {
    unsigned uu[8];
    #pragma unroll
    for (int j = 0; j < 8; ++j)
      uu[j] = (unsigned)f32_bf16(v[2*j]*inv) | ((unsigned)f32_bf16(v[2*j+1]*inv) << 16);
    ((uint4*)ph)[0] = make_uint4(uu[0], uu[1], uu[2], uu[3]);
    ((uint4*)ph)[1] = make_uint4(uu[4], uu[5], uu[6], uu[7]);
  }
}

// --------------------------- elementwise helpers ---------------------------
__global__ __launch_bounds__(256) void copy_pm_k(const float4* __restrict__ pm, float4* __restrict__ comb)
{
  const int idx = blockIdx.x * 256 + threadIdx.x;        // 16384 = 4*32*128
  const int b = idx >> 12, rem = idx & 4095;
  const int r = rem >> 7, d = rem & 127;
  comb[((b << 10) + r) * 128 + d] = pm[(r << 7) + d];
}

__global__ __launch_bounds__(256) void copy_chunk_k(const float4* __restrict__ x, float4* __restrict__ comb, int ci)
{
  const int idx = blockIdx.x * 256 + threadIdx.x;        // 253952 = 4*496*128
  const int b = idx / 63488, rem = idx % 63488;
  const int r = rem >> 7, d = rem & 127;
  comb[((b << 10) + 528 + r) * 128 + d] = x[(long long)(b * 3968 + ci * 496 + r) * 128 + d];
}

__global__ __launch_bounds__(256) void ema_k(float4* __restrict__ mem, const float4* __restrict__ att)
{
  const int idx = blockIdx.x * 256 + threadIdx.x;        // 524288
  float4 m = mem[idx];
  const float4 a = att[idx];
  m.x = 0.9f*m.x + 0.1f*a.x; m.y = 0.9f*m.y + 0.1f*a.y;
  m.z = 0.9f*m.z + 0.1f*a.z; m.w = 0.9f*m.w + 0.1f*a.w;
  mem[idx] = m;
}

__global__ __launch_bounds__(256) void outmul_k(const float4* __restrict__ att, const float4* __restrict__ mo,
                                                float4* __restrict__ out, int ci)
{
  const int idx = blockIdx.x * 256 + threadIdx.x;        // 253952
  const int b = idx / 63488, rem = idx % 63488;
  const int r = rem >> 7, d = rem & 127;
  const long long src = (long long)((b << 10) + 528 + r) * 128 + d;
  const float4 a = att[src], m = mo[src];
  float4 o;
  o.x = a.x*m.x; o.y = a.y*m.y; o.z = a.z*m.z; o.w = a.w*m.w;
  out[(long long)(b * 3968 + ci * 496 + r) * 128 + d] = o;
}

// ---------------------------------------------------------------------------
extern "C" void kernel_launch(void* const* d_in, const int* in_sizes, int n_in,
                              void* d_out, int out_size, void* d_ws, size_t ws_size,
                              hipStream_t stream)
{
  (void)in_sizes; (void)n_in; (void)out_size; (void)ws_size;
  const float* x   = (const float*)d_in[0];
  const float* pm  = (const float*)d_in[1];
  const float* Wq  = (const float*)d_in[2];
  const float* bq  = (const float*)d_in[3];
  const float* mkw = (const float*)d_in[4];
  const float* mkb = (const float*)d_in[5];
  const float* mvw = (const float*)d_in[6];
  const float* mvb = (const float*)d_in[7];
  const float* mqw = (const float*)d_in[8];
  const float* mqb = (const float*)d_in[9];
  const float* aqb_w = (const float*)d_in[10];
  const float* aqb = (const float*)d_in[11];
  const float* akw = (const float*)d_in[12];
  const float* akb = (const float*)d_in[13];
  const float* avw = (const float*)d_in[14];
  const float* avb = (const float*)d_in[15];
  const float* aow = (const float*)d_in[16];
  const float* aob = (const float*)d_in[17];
  float* out = (float*)d_out;

  char* wsp = (char*)d_ws;
  size_t off = 0;
  auto alloc = [&](size_t b) -> void* { void* p = wsp + off; off += (b + 255) & ~(size_t)255; return p; };

  unsigned short* WT[8];
  for (int i = 0; i < 8; ++i) WT[i] = (unsigned short*)alloc(512 * 512 * 2);   // bf16 [N][K]
  float* mem  = (float*)alloc(8388608);          // [4,1024,512]
  float* Q    = (float*)alloc(4063232);          // [4,496,512]
  float* QP   = (float*)alloc(8388608);
  float* Kb   = (float*)alloc(8388608);
  float* Vb   = (float*)alloc(8388608);
  float* comb = (float*)alloc(8388608);          // [pm(32) | hist(496) | chunk(496)]
  float* OH   = (float*)alloc(8388608);
  float* ATT  = (float*)alloc(8388608);
  unsigned short* VT  = (unsigned short*)alloc(4194304);   // bf16 [4,512,1024]
  float* SC   = (float*)alloc(16777216);         // f32 [4,1024,1024]
  unsigned short* SCH = (unsigned short*)alloc(67108864);  // fp16/bf16 [32,1024,1024]

  const long long XBS = 2031616, BS = 524288, QBS = 253952, SCS = 1048576;
  const float sr = 0.044194173824159216f;        // 1/sqrt(512)
  const float shs = 0.125f;                      // 1/sqrt(64)

  hipMemsetAsync(mem, 0, 8388608, stream);
  const float* Wsrc[8] = {Wq, mkw, mvw, mqw, aqb_w, akw, avw, aow};
  for (int i = 0; i < 8; ++i)
    transpose_f32_bf16<<<dim3(16, 16, 1), 256, 0, stream>>>(Wsrc[i], WT[i], 512, 512, 0, 0);
  copy_pm_k<<<64, 256, 0, stream>>>((const float4*)pm, (float4*)comb);

  for (int ci = 0; ci < 8; ++ci) {
    copy_chunk_k<<<992, 256, 0, stream>>>((const float4*)x, (float4*)comb, ci);

    // query = chunk @ Wq + bq
    gemm_abt<128,128,0,1,0,true,true><<<dim3(4,4,4),256,0,stream>>>(
      x + (long long)ci * 253952, XBS, 0, 512, WT[0], 0, 0, 512,
      Q, QBS, 0, 512, bq, 1.0f, 496, 512, 1);
    // retrieve(mem, query): qp / k / v
    gemm_abt<128,128,0,1,0,true,true><<<dim3(4,4,4),256,0,stream>>>(
      Q, QBS, 0, 512, WT[3], 0, 0, 512, QP, BS, 0, 512, mqb, 1.0f, 496, 512, 1);
    gemm_abt<128,128,0,1,0,false,true><<<dim3(8,4,4),256,0,stream>>>(
      mem, BS, 0, 512, WT[1], 0, 0, 512, Kb, BS, 0, 512, mkb, 1.0f, 1024, 512, 1);
    gemm_abt<128,128,0,1,0,false,true><<<dim3(8,4,4),256,0,stream>>>(
      mem, BS, 0, 512, WT[2], 0, 0, 512, Vb, BS, 0, 512, mvb, 1.0f, 1024, 512, 1);
    transpose_f32_bf16<<<dim3(16,32,4),256,0,stream>>>(Vb, VT, 1024, 512, BS, BS);
    gemm_abt<128,128,0,0,0,true,false><<<dim3(4,8,4),256,0,stream>>>(
      QP, BS, 0, 512, Kb, BS, 0, 512, SC, SCS, 0, 1024, nullptr, sr, 496, 512, 1);
    softmax_rows<0><<<496,256,0,stream>>>(SC, 496, SCS);
    gemm_abt<128,128,0,1,0,true,false><<<dim3(4,4,4),256,0,stream>>>(
      SC, SCS, 0, 1024, VT, BS, 0, 1024, comb + 32 * 512, BS, 0, 512, nullptr, 1.0f, 496, 1024, 1);

    // mha(combined): q/k/v projections
    gemm_abt<128,128,0,1,0,false,true><<<dim3(8,4,4),256,0,stream>>>(
      comb, BS, 0, 512, WT[4], 0, 0, 512, QP, BS, 0, 512, aqb, 1.0f, 1024, 512, 1);
    gemm_abt<128,128,0,1,0,false,true><<<dim3(8,4,4),256,0,stream>>>(
      comb, BS, 0, 512, WT[5], 0, 0, 512, Kb, BS, 0, 512, akb, 1.0f, 1024, 512, 1);
    gemm_abt<128,128,0,1,0,false,true><<<dim3(8,4,4),256,0,stream>>>(
      comb, BS, 0, 512, WT[6], 0, 0, 512, Vb, BS, 0, 512, avb, 1.0f, 1024, 512, 1);
    transpose_f32_bf16<<<dim3(16,32,4),256,0,stream>>>(Vb, VT, 1024, 512, BS, BS);
    // per-head scores (fp16 out), softmax (-> bf16 in place), PV (N=64 per head)
    gemm_abt<128,128,0,0,1,false,false><<<dim3(8,8,32),256,0,stream>>>(
      QP, BS, 64, 512, Kb, BS, 64, 512, SCH, 8 * SCS, SCS, 1024, nullptr, shs, 1024, 64, 8);
    softmax_rows<1><<<8192,256,0,stream>>>(SCH, 1024, SCS);
    gemm_abt<128,64,1,1,0,false,false><<<dim3(8,1,32),256,0,stream>>>(
      SCH, 8 * SCS, SCS, 1024, VT, BS, 65536, 1024, OH, BS, 64, 512, nullptr, 1.0f, 1024, 1024, 8);
    gemm_abt<128,128,0,1,0,false,true><<<dim3(8,4,4),256,0,stream>>>(
      OH, BS, 0, 512, WT[7], 0, 0, 512, ATT, BS, 0, 512, aob, 1.0f, 1024, 512, 1);

    // mem = 0.9*mem + 0.1*attended
    ema_k<<<2048,256,0,stream>>>((float4*)mem, (const float4*)ATT);

    // retrieve(mem2, attended)
    gemm_abt<128,128,0,1,0,false,true><<<dim3(8,4,4),256,0,stream>>>(
      ATT, BS, 0, 512, WT[3], 0, 0, 512, QP, BS, 0, 512, mqb, 1.0f, 1024, 512, 1);
    gemm_abt<128,128,0,1,0,false,true><<<dim3(8,4,4),256,0,stream>>>(
      mem, BS, 0, 512, WT[1], 0, 0, 512, Kb, BS, 0, 512, mkb, 1.0f, 1024, 512, 1);
    gemm_abt<128,128,0,1,0,false,true><<<dim3(8,4,4),256,0,stream>>>(
      mem, BS, 0, 512, WT[2], 0, 0, 512, Vb, BS, 0, 512, mvb, 1.0f, 1024, 512, 1);
    transpose_f32_bf16<<<dim3(16,32,4),256,0,stream>>>(Vb, VT, 1024, 512, BS, BS);
    gemm_abt<128,128,0,0,0,false,false><<<dim3(8,8,4),256,0,stream>>>(
      QP, BS, 0, 512, Kb, BS, 0, 512, SC, SCS, 0, 1024, nullptr, sr, 1024, 512, 1);
    softmax_rows<0><<<1024,256,0,stream>>>(SC, 1024, SCS);
    gemm_abt<128,128,0,1,0,false,false><<<dim3(8,4,4),256,0,stream>>>(
      SC, SCS, 0, 1024, VT, BS, 0, 1024, OH, BS, 0, 512, nullptr, 1.0f, 1024, 1024, 1);

    // out = (attended * mout)[:, -496:]
    outmul_k<<<992,256,0,stream>>>((const float4*)ATT, (const float4*)OH, (float4*)out, ci);
  }
}

// Round 3
// 1895.776 us; speedup vs baseline: 2.4366x; 2.4366x over previous
//
#include <hip/hip_runtime.h>
#include <hip/hip_fp16.h>

// MemoryAsContextTitan: B=4, S=3968, D=512, H=8, HD=64, CHUNK=496, NPM=32, MEM=1024, nch=8
// R3 = R2 with the Hh-indexing bug fixed (batched GEMM calls must pass Hh=1 so zb=z).
// bf16 activations, double-buffered BK=64 GEMM with register prefetch, fused KV / QKV
// projections, transposed-V store in epilogue, retrieve-2 truncated to last 496 rows.

typedef __attribute__((ext_vector_type(8))) short short8;
typedef __attribute__((ext_vector_type(4))) float f32x4;

static __device__ __forceinline__ unsigned short f32_bf16(float f) {
  unsigned int u = __float_as_uint(f);
  u += 0x7FFFu + ((u >> 16) & 1u);            // RNE
  return (unsigned short)(u >> 16);
}
static __device__ __forceinline__ unsigned pk(float lo, float hi) {
  return (unsigned)f32_bf16(lo) | ((unsigned)f32_bf16(hi) << 16);
}

// ---------------------------------------------------------------------------
// GEMM: C[z][m][n] = scale * sum_k A[z][m][k] * Bt[z][n][k]  (+ bias[n])
// Row bases: base + (z/Hh)*sb + (z%Hh)*sh + row*rs (elements). K-major rows.
// ATY/BTY: 0 = f32 source (convert to bf16), 1 = bf16 source.
// CTY: 0 f32, 1 fp16, 2 bf16, 4 split: col<csplit -> bf16 normal to Cp,
//      col>=csplit -> bf16 TRANSPOSED to Cp2 as VT[b][col-csplit][row&1023]
//      (batch = row>>10, VT strides hardcoded 524288 / 1024).
// Double-buffered BK=64, register-prefetch staging. Kdim % 64 == 0.
// ---------------------------------------------------------------------------
template<int BM, int BN, int ATY, int BTY, int CTY, bool GUARD, bool BIAS>
__global__ __launch_bounds__(256) void gemm2(
    const void* __restrict__ Ap, long long Asb, long long Ash, int Ars,
    const void* __restrict__ Bp, long long Bsb, long long Bsh, int Brs,
    void* __restrict__ Cp, long long Csb, long long Csh, int Crs,
    void* __restrict__ Cp2, int csplit,
    const float* __restrict__ bias, float scale, int M, int Kdim, int Hh)
{
  constexpr int LDP = 72;                       // 64 + 8 pad
  constexpr int WN = (BN >= 128) ? 2 : (BM >= 128 ? 1 : 2);
  constexpr int WM = 4 / WN;
  constexpr int MI = BM / (WM * 16);
  constexpr int NI = BN / (WN * 16);
  constexpr int AP = BM / 32;
  constexpr int BP = BN / 32;

  __shared__ unsigned short As[2][BM][LDP];
  __shared__ unsigned short Bs[2][BN][LDP];

  const int tid  = threadIdx.x;
  const int lane = tid & 63;
  const int w    = tid >> 6;
  const int wm   = w / WN, wn = w % WN;
  const int z    = blockIdx.z;
  const int zb   = z / Hh, zh = z - zb * Hh;
  const int m0   = blockIdx.x * BM;
  const int n0   = blockIdx.y * BN;
  const int lrow = lane & 15;
  const int lkB  = (lane >> 4) * 8;
  const int srow = tid >> 3;                    // 0..31
  const int scol = (tid & 7) * 8;               // 0..56

  const float*          Af  = (const float*)Ap          + zb * Asb + zh * Ash;
  const unsigned short* Ahp = (const unsigned short*)Ap + zb * Asb + zh * Ash;
  const float*          Bf  = (const float*)Bp          + zb * Bsb + zh * Bsh;
  const unsigned short* Bhp = (const unsigned short*)Bp + zb * Bsb + zh * Bsh;

  float4 afl[AP][2]; uint4 ahl[AP];
  float4 bfl[BP][2]; uint4 bhl[BP];

  auto loadT = [&](int k0) {
    #pragma unroll
    for (int p = 0; p < AP; ++p) {
      const int row = srow + p * 32;
      const bool ok = !GUARD || (m0 + row) < M;
      if constexpr (ATY == 0) {
        if (ok) {
          const float* s = Af + (long long)(m0 + row) * Ars + k0 + scol;
          afl[p][0] = *(const float4*)s;
          afl[p][1] = *(const float4*)(s + 4);
        } else {
          afl[p][0] = make_float4(0.f,0.f,0.f,0.f);
          afl[p][1] = make_float4(0.f,0.f,0.f,0.f);
        }
      } else {
        ahl[p] = ok ? *(const uint4*)(Ahp + (long long)(m0 + row) * Ars + k0 + scol)
                    : make_uint4(0u,0u,0u,0u);
      }
    }
    #pragma unroll
    for (int p = 0; p < BP; ++p) {
      const int row = srow + p * 32;
      if constexpr (BTY == 0) {
        const float* s = Bf + (long long)(n0 + row) * Brs + k0 + scol;
        bfl[p][0] = *(const float4*)s;
        bfl[p][1] = *(const float4*)(s + 4);
      } else {
        bhl[p] = *(const uint4*)(Bhp + (long long)(n0 + row) * Brs + k0 + scol);
      }
    }
  };
  auto writeT = [&](int buf) {
    #pragma unroll
    for (int p = 0; p < AP; ++p) {
      const int row = srow + p * 32;
      uint4 u;
      if constexpr (ATY == 0) {
        u.x = pk(afl[p][0].x, afl[p][0].y); u.y = pk(afl[p][0].z, afl[p][0].w);
        u.z = pk(afl[p][1].x, afl[p][1].y); u.w = pk(afl[p][1].z, afl[p][1].w);
      } else u = ahl[p];
      *(uint4*)(&As[buf][row][scol]) = u;
    }
    #pragma unroll
    for (int p = 0; p < BP; ++p) {
      const int row = srow + p * 32;
      uint4 u;
      if constexpr (BTY == 0) {
        u.x = pk(bfl[p][0].x, bfl[p][0].y); u.y = pk(bfl[p][0].z, bfl[p][0].w);
        u.z = pk(bfl[p][1].x, bfl[p][1].y); u.w = pk(bfl[p][1].z, bfl[p][1].w);
      } else u = bhl[p];
      *(uint4*)(&Bs[buf][row][scol]) = u;
    }
  };

  f32x4 acc[MI][NI] = {};

  loadT(0);
  writeT(0);
  __syncthreads();

  const int NT = Kdim >> 6;
  int cur = 0;
  for (int t = 0; t < NT; ++t) {
    const bool more = (t + 1) < NT;
    if (more) loadT((t + 1) << 6);              // global loads for next tile

    short8 a8[MI][2], b8[NI][2];
    #pragma unroll
    for (int mi = 0; mi < MI; ++mi) {
      const unsigned short* r = &As[cur][wm * (MI * 16) + mi * 16 + lrow][lkB];
      a8[mi][0] = *(const short8*)r;
      a8[mi][1] = *(const short8*)(r + 32);
    }
    #pragma unroll
    for (int ni = 0; ni < NI; ++ni) {
      const unsigned short* r = &Bs[cur][wn * (NI * 16) + ni * 16 + lrow][lkB];
      b8[ni][0] = *(const short8*)r;
      b8[ni][1] = *(const short8*)(r + 32);
    }
    #pragma unroll
    for (int kk = 0; kk < 2; ++kk)
      #pragma unroll
      for (int mi = 0; mi < MI; ++mi)
        #pragma unroll
        for (int ni = 0; ni < NI; ++ni)
          acc[mi][ni] = __builtin_amdgcn_mfma_f32_16x16x32_bf16(a8[mi][kk], b8[ni][kk], acc[mi][ni], 0, 0, 0);

    if (more) writeT(cur ^ 1);                  // waits vmcnt, fills other buffer
    __syncthreads();
    cur ^= 1;
  }

  // ---- epilogue: D[row][col], row=(lane>>4)*4+r, col=lane&15 ----
  float*          Cf  = (float*)Cp          + zb * Csb + zh * Csh;
  unsigned short* Chn = (unsigned short*)Cp + zb * Csb + zh * Csh;
  unsigned short* Ch2 = (unsigned short*)Cp2;
  const bool trside = (CTY == 4) ? (n0 >= csplit) : false;

  #pragma unroll
  for (int ni = 0; ni < NI; ++ni) {
    const int col = n0 + wn * (NI * 16) + ni * 16 + lrow;
    const float bv = BIAS ? bias[col] : 0.0f;
    #pragma unroll
    for (int mi = 0; mi < MI; ++mi) {
      const int rbase = m0 + wm * (MI * 16) + mi * 16 + ((lane >> 4) << 2);
      if (trside) {
        ushort4 v;
        v.x = f32_bf16(acc[mi][ni][0] * scale + bv);
        v.y = f32_bf16(acc[mi][ni][1] * scale + bv);
        v.z = f32_bf16(acc[mi][ni][2] * scale + bv);
        v.w = f32_bf16(acc[mi][ni][3] * scale + bv);
        const long long dst = (long long)(rbase >> 10) * 524288
                            + (long long)(col - csplit) * 1024 + (rbase & 1023);
        *(ushort4*)(&Ch2[dst]) = v;
      } else {
        #pragma unroll
        for (int r = 0; r < 4; ++r) {
          const int row = rbase + r;
          if (!GUARD || row < M) {
            const float v = acc[mi][ni][r] * scale + bv;
            if constexpr (CTY == 0)      Cf [(long long)row * Crs + col] = v;
            else if constexpr (CTY == 1) Chn[(long long)row * Crs + col] = __half_as_ushort(__float2half(v));
            else                         Chn[(long long)row * Crs + col] = f32_bf16(v);
          }
        }
      }
    }
  }
}

// ---------------------------------------------------------------------------
// Weight transpose + f32->bf16: out[c][r] = in[r][c]. R,C multiples of 32.
// ---------------------------------------------------------------------------
__global__ __launch_bounds__(256) void transpose_f32_bf16(
    const float* __restrict__ in, unsigned short* __restrict__ out, int R, int C)
{
  __shared__ float tile[32][33];
  const int c0 = blockIdx.x * 32, r0 = blockIdx.y * 32;
  const int xx = threadIdx.x & 31, ys = threadIdx.x >> 5;
  #pragma unroll
  for (int yy = ys; yy < 32; yy += 8)
    tile[yy][xx] = in[(long long)(r0 + yy) * C + c0 + xx];
  __syncthreads();
  #pragma unroll
  for (int yy = ys; yy < 32; yy += 8)
    out[(long long)(c0 + yy) * R + r0 + xx] = f32_bf16(tile[xx][yy]);
}

// ---------------------------------------------------------------------------
// Row softmax, row length 1024, one wave per row (4 rows/block).
// IOTY 0: f32 in -> f32 out.  IOTY 1: fp16 in -> bf16 out (same 2-byte slots).
// ---------------------------------------------------------------------------
template<int IOTY>
__global__ __launch_bounds__(256) void softmax_rows(void* __restrict__ buf, int rowsPerZ, long long zStride)
{
  const int gr   = blockIdx.x * 4 + (threadIdx.x >> 6);
  const int lane = threadIdx.x & 63;
  const int z = gr / rowsPerZ;
  const int i = gr - z * rowsPerZ;
  float v[16];
  float* pf = nullptr;
  unsigned short* ph = nullptr;
  if constexpr (IOTY == 0) {
    pf = (float*)buf + (long long)z * zStride + (long long)i * 1024 + lane * 16;
    #pragma unroll
    for (int j = 0; j < 4; ++j) {
      const float4 f = ((const float4*)pf)[j];
      v[4*j+0] = f.x; v[4*j+1] = f.y; v[4*j+2] = f.z; v[4*j+3] = f.w;
    }
  } else {
    ph = (unsigned short*)buf + (long long)z * zStride + (long long)i * 1024 + lane * 16;
    const uint4 u0 = ((const uint4*)ph)[0];
    const uint4 u1 = ((const uint4*)ph)[1];
    const unsigned uu[8] = {u0.x, u0.y, u0.z, u0.w, u1.x, u1.y, u1.z, u1.w};
    #pragma unroll
    for (int j = 0; j < 8; ++j) {
      v[2*j]   = __half2float(__ushort_as_half((unsigned short)(uu[j] & 0xffffu)));
      v[2*j+1] = __half2float(__ushort_as_half((unsigned short)(uu[j] >> 16)));
    }
  }
  float mx = v[0];
  #pragma unroll
  for (int j = 1; j < 16; ++j) mx = fmaxf(mx, v[j]);
  #pragma unroll
  for (int d = 32; d; d >>= 1) mx = fmaxf(mx, __shfl_xor(mx, d));
  float s = 0.0f;
  #pragma unroll
  for (int j = 0; j < 16; ++j) { v[j] = __expf(v[j] - mx); s += v[j]; }
  #pragma unroll
  for (int d = 32; d; d >>= 1) s += __shfl_xor(s, d);
  const float inv = 1.0f / s;
  if constexpr (IOTY == 0) {
    #pragma unroll
    for (int j = 0; j < 4; ++j) {
      float4 f;
      f.x = v[4*j+0]*inv; f.y = v[4*j+1]*inv; f.z = v[4*j+2]*inv; f.w = v[4*j+3]*inv;
      ((float4*)pf)[j] = f;
    }
  } else {
    unsigned uu[8];
    #pragma unroll
    for (int j = 0; j < 8; ++j)
      uu[j] = pk(v[2*j]*inv, v[2*j+1]*inv);
    ((uint4*)ph)[0] = make_uint4(uu[0], uu[1], uu[2], uu[3]);
    ((uint4*)ph)[1] = make_uint4(uu[4], uu[5], uu[6], uu[7]);
  }
}

// --------------------------- elementwise helpers ---------------------------
__global__ __launch_bounds__(256) void copy_pm_bf(const float* __restrict__ pm, unsigned short* __restrict__ comb)
{
  const int idx = blockIdx.x * 256 + threadIdx.x;   // 8192 = 4*32*512/8
  const int b = idx >> 11, e = idx & 2047;
  const int row = e >> 6, d8 = (e & 63) * 8;
  const float* s = pm + row * 512 + d8;
  const float4 f0 = *(const float4*)s;
  const float4 f1 = *(const float4*)(s + 4);
  uint4 u; u.x = pk(f0.x, f0.y); u.y = pk(f0.z, f0.w); u.z = pk(f1.x, f1.y); u.w = pk(f1.z, f1.w);
  *(uint4*)(comb + (long long)b * 524288 + row * 512 + d8) = u;
}

__global__ __launch_bounds__(256) void copy_chunk_bf(const float* __restrict__ x, unsigned short* __restrict__ comb, int ci)
{
  const int idx = blockIdx.x * 256 + threadIdx.x;   // 126976 = 4*496*512/8
  const int b = idx / 31744, e = idx % 31744;
  const int row = e >> 6, d8 = (e & 63) * 8;
  const float* s = x + ((long long)b * 3968 + ci * 496 + row) * 512 + d8;
  const float4 f0 = *(const float4*)s;
  const float4 f1 = *(const float4*)(s + 4);
  uint4 u; u.x = pk(f0.x, f0.y); u.y = pk(f0.z, f0.w); u.z = pk(f1.x, f1.y); u.w = pk(f1.z, f1.w);
  *(uint4*)(comb + (long long)b * 524288 + (528 + row) * 512 + d8) = u;
}

__global__ __launch_bounds__(256) void ema_k(float4* __restrict__ mem, const float4* __restrict__ att)
{
  const int idx = blockIdx.x * 256 + threadIdx.x;   // 524288
  float4 m = mem[idx];
  const float4 a = att[idx];
  m.x = 0.9f*m.x + 0.1f*a.x; m.y = 0.9f*m.y + 0.1f*a.y;
  m.z = 0.9f*m.z + 0.1f*a.z; m.w = 0.9f*m.w + 0.1f*a.w;
  mem[idx] = m;
}

__global__ __launch_bounds__(256) void outmul_k(const float4* __restrict__ att, const float4* __restrict__ mo,
                                                float4* __restrict__ out, int ci)
{
  const int idx = blockIdx.x * 256 + threadIdx.x;   // 253952 = 4*496*128
  const int b = idx / 63488, rem = idx % 63488;
  const int r = rem >> 7, d = rem & 127;
  const float4 a = att[(long long)((b << 10) + 528 + r) * 128 + d];
  const float4 m = mo[(long long)(b * 496 + r) * 128 + d];
  float4 o;
  o.x = a.x*m.x; o.y = a.y*m.y; o.z = a.z*m.z; o.w = a.w*m.w;
  out[(long long)(b * 3968 + ci * 496 + r) * 128 + d] = o;
}

// ---------------------------------------------------------------------------
extern "C" void kernel_launch(void* const* d_in, const int* in_sizes, int n_in,
                              void* d_out, int out_size, void* d_ws, size_t ws_size,
                              hipStream_t stream)
{
  (void)in_sizes; (void)n_in; (void)out_size; (void)ws_size;
  const float* x   = (const float*)d_in[0];
  const float* pm  = (const float*)d_in[1];
  const float* Wq  = (const float*)d_in[2];
  const float* bq  = (const float*)d_in[3];
  const float* mkw = (const float*)d_in[4];
  const float* mkb = (const float*)d_in[5];
  const float* mvw = (const float*)d_in[6];
  const float* mvb = (const float*)d_in[7];
  const float* mqw = (const float*)d_in[8];
  const float* mqb = (const float*)d_in[9];
  const float* aqw = (const float*)d_in[10];
  const float* aqb = (const float*)d_in[11];
  const float* akw = (const float*)d_in[12];
  const float* akb = (const float*)d_in[13];
  const float* avw = (const float*)d_in[14];
  const float* avb = (const float*)d_in[15];
  const float* aow = (const float*)d_in[16];
  const float* aob = (const float*)d_in[17];
  float* out = (float*)d_out;

  char* wsp = (char*)d_ws;
  size_t off = 0;
  auto alloc = [&](size_t b) -> void* { void* p = wsp + off; off += (b + 255) & ~(size_t)255; return p; };

  unsigned short* WT0  = (unsigned short*)alloc(524288);       // Wq^T   [512][512]
  unsigned short* WTmq = (unsigned short*)alloc(524288);       // mq^T
  unsigned short* WKV  = (unsigned short*)alloc(1048576);      // [mk;mv]^T [1024][512]
  unsigned short* WQKV = (unsigned short*)alloc(1572864);      // [aq;ak;av]^T [1536][512]
  unsigned short* WTao = (unsigned short*)alloc(524288);       // ao^T
  float* bkv  = (float*)alloc(4096);                           // [1024]
  float* bqkv = (float*)alloc(6144);                           // [1536]
  float*          mem  = (float*)alloc(8388608);               // f32 [4,1024,512]
  unsigned short* Q    = (unsigned short*)alloc(2031616);      // bf16 [4,496,512]
  unsigned short* QP   = (unsigned short*)alloc(2031616);      // bf16 [4,496,512]
  unsigned short* Kb   = (unsigned short*)alloc(4194304);      // bf16 [4,1024,512]
  unsigned short* comb = (unsigned short*)alloc(4194304);      // bf16 [4,1024,512]
  unsigned short* QKb  = (unsigned short*)alloc(8388608);      // bf16 [4,1024,1024] (q|k)
  unsigned short* VT   = (unsigned short*)alloc(4194304);      // bf16 [4,512,1024]
  unsigned short* OH   = (unsigned short*)alloc(4194304);      // bf16 [4,1024,512]
  float*          ATT  = (float*)alloc(8388608);               // f32 [4,1024,512]
  float*          OH2  = (float*)alloc(4063232);               // f32 [4,496,512]
  float*          SC   = (float*)alloc(8126464);               // f32 [4,496,1024]
  unsigned short* SCH  = (unsigned short*)alloc(67108864);     // fp16/bf16 [32,1024,1024]

  const long long XBS = 2031616, BS = 524288, QBS = 253952;
  const long long SCB = 507904;                 // 496*1024
  const long long SCHS = 1048576, SCHB = 8388608;
  const float sr  = 0.044194173824159216f;      // 1/sqrt(512)
  const float shs = 0.125f;                     // 1/sqrt(64)

  // -------- prep (once per call) --------
  hipMemsetAsync(mem, 0, 8388608, stream);
  transpose_f32_bf16<<<dim3(16,16,1),256,0,stream>>>(Wq,  WT0,            512, 512);
  transpose_f32_bf16<<<dim3(16,16,1),256,0,stream>>>(mqw, WTmq,           512, 512);
  transpose_f32_bf16<<<dim3(16,16,1),256,0,stream>>>(mkw, WKV,            512, 512);
  transpose_f32_bf16<<<dim3(16,16,1),256,0,stream>>>(mvw, WKV  + 262144,  512, 512);
  transpose_f32_bf16<<<dim3(16,16,1),256,0,stream>>>(aqw, WQKV,           512, 512);
  transpose_f32_bf16<<<dim3(16,16,1),256,0,stream>>>(akw, WQKV + 262144,  512, 512);
  transpose_f32_bf16<<<dim3(16,16,1),256,0,stream>>>(avw, WQKV + 524288,  512, 512);
  transpose_f32_bf16<<<dim3(16,16,1),256,0,stream>>>(aow, WTao,           512, 512);
  hipMemcpyAsync(bkv,        mkb, 2048, hipMemcpyDeviceToDevice, stream);
  hipMemcpyAsync(bkv  + 512, mvb, 2048, hipMemcpyDeviceToDevice, stream);
  hipMemcpyAsync(bqkv,       aqb, 2048, hipMemcpyDeviceToDevice, stream);
  hipMemcpyAsync(bqkv + 512, akb, 2048, hipMemcpyDeviceToDevice, stream);
  hipMemcpyAsync(bqkv +1024, avb, 2048, hipMemcpyDeviceToDevice, stream);
  copy_pm_bf<<<32,256,0,stream>>>(pm, comb);

  for (int ci = 0; ci < 8; ++ci) {
    copy_chunk_bf<<<496,256,0,stream>>>(x, comb, ci);

    // query = chunk @ Wq + bq   -> Q bf16 [4,496,512]
    gemm2<64,64,0,1,2,true,true><<<dim3(8,8,4),256,0,stream>>>(
      x + (long long)ci * 253952, XBS, 0, 512, WT0, 0, 0, 512,
      Q, QBS, 0, 512, nullptr, 0, bq, 1.0f, 496, 512, 1);
    // qp1 = query @ mq + mqb    -> QP bf16
    gemm2<64,64,1,1,2,true,true><<<dim3(8,8,4),256,0,stream>>>(
      Q, QBS, 0, 512, WTmq, 0, 0, 512,
      QP, QBS, 0, 512, nullptr, 0, mqb, 1.0f, 496, 512, 1);
    // [K|V] = mem @ [mk|mv] + [mkb|mvb]; K -> Kb bf16, V -> VT transposed
    gemm2<128,64,0,1,4,false,true><<<dim3(32,16,1),256,0,stream>>>(
      mem, 0, 0, 512, WKV, 0, 0, 512,
      Kb, 0, 0, 512, VT, 512, bkv, 1.0f, 4096, 512, 1);
    // scores1 = qp @ k^T / sqrt(D) -> SC f32 [4,496,1024]
    gemm2<64,64,1,1,0,true,false><<<dim3(8,16,4),256,0,stream>>>(
      QP, QBS, 0, 512, Kb, BS, 0, 512,
      SC, SCB, 0, 1024, nullptr, 0, nullptr, sr, 496, 512, 1);
    softmax_rows<0><<<496,256,0,stream>>>(SC, 496, SCB);
    // hist = probs @ V -> comb rows 32..527 (bf16)
    gemm2<64,64,0,1,2,true,false><<<dim3(8,8,4),256,0,stream>>>(
      SC, SCB, 0, 1024, VT, BS, 0, 1024,
      comb + 32 * 512, BS, 0, 512, nullptr, 0, nullptr, 1.0f, 496, 1024, 1);

    // MHA qkv: comb @ [aq|ak|av]; q|k -> QKb [4,1024,1024], v -> VT transposed
    gemm2<128,64,1,1,4,false,true><<<dim3(32,24,1),256,0,stream>>>(
      comb, 0, 0, 512, WQKV, 0, 0, 512,
      QKb, 0, 0, 1024, VT, 1024, bqkv, 1.0f, 4096, 512, 1);
    // per-head scores (fp16) : z=(b,h), K=64
    gemm2<128,64,1,1,1,false,false><<<dim3(8,16,32),256,0,stream>>>(
      QKb, 1048576, 64, 1024, QKb + 512, 1048576, 64, 1024,
      SCH, SCHB, SCHS, 1024, nullptr, 0, nullptr, shs, 1024, 64, 8);
    softmax_rows<1><<<8192,256,0,stream>>>(SCH, 1024, SCHS);
    // PV per head -> OH bf16 [4,1024,512]
    gemm2<128,64,1,1,2,false,false><<<dim3(8,1,32),256,0,stream>>>(
      SCH, SCHB, SCHS, 1024, VT, BS, 65536, 1024,
      OH, BS, 64, 512, nullptr, 0, nullptr, 1.0f, 1024, 1024, 8);
    // attended = OH @ ao + aob -> ATT f32
    gemm2<128,64,1,1,0,false,true><<<dim3(32,8,1),256,0,stream>>>(
      OH, 0, 0, 512, WTao, 0, 0, 512,
      ATT, 0, 0, 512, nullptr, 0, aob, 1.0f, 4096, 512, 1);

    // mem = 0.9*mem + 0.1*attended
    ema_k<<<2048,256,0,stream>>>((float4*)mem, (const float4*)ATT);

    // retrieve2 (only last 496 rows needed): qp2 = ATT[:,528:] @ mq + mqb
    gemm2<64,64,0,1,2,true,true><<<dim3(8,8,4),256,0,stream>>>(
      ATT + 528 * 512, BS, 0, 512, WTmq, 0, 0, 512,
      QP, QBS, 0, 512, nullptr, 0, mqb, 1.0f, 496, 512, 1);
    gemm2<128,64,0,1,4,false,true><<<dim3(32,16,1),256,0,stream>>>(
      mem, 0, 0, 512, WKV, 0, 0, 512,
      Kb, 0, 0, 512, VT, 512, bkv, 1.0f, 4096, 512, 1);
    gemm2<64,64,1,1,0,true,false><<<dim3(8,16,4),256,0,stream>>>(
      QP, QBS, 0, 512, Kb, BS, 0, 512,
      SC, SCB, 0, 1024, nullptr, 0, nullptr, sr, 496, 512, 1);
    softmax_rows<0><<<496,256,0,stream>>>(SC, 496, SCB);
    gemm2<64,64,0,1,0,true,false><<<dim3(8,8,4),256,0,stream>>>(
      SC, SCB, 0, 1024, VT, BS, 0, 1024,
      OH2, QBS, 0, 512, nullptr, 0, nullptr, 1.0f, 496, 1024, 1);

    // out = (attended * mout)[:, -496:]
    outmul_k<<<992,256,0,stream>>>((const float4*)ATT, (const float4*)OH2, (float4*)out, ci);
  }
}

// Round 4
// 1504.912 us; speedup vs baseline: 3.0695x; 1.2597x over previous
//
#include <hip/hip_runtime.h>
#include <hip/hip_fp16.h>

// MemoryAsContextTitan: B=4, S=3968, D=512, H=8, HD=64, CHUNK=496, NPM=32, MEM=1024, nch=8
// R4: flash-MHA (no score materialization), KV maintained in EMA form (mem eliminated),
// fused Wq*mq weight, softmax->bf16 buffer. 14 dispatches/step.

typedef __attribute__((ext_vector_type(8))) short short8;
typedef __attribute__((ext_vector_type(4))) float f32x4;

static __device__ __forceinline__ unsigned short f32_bf16(float f) {
  unsigned int u = __float_as_uint(f);
  u += 0x7FFFu + ((u >> 16) & 1u);            // RNE
  return (unsigned short)(u >> 16);
}
static __device__ __forceinline__ unsigned pk(float lo, float hi) {
  return (unsigned)f32_bf16(lo) | ((unsigned)f32_bf16(hi) << 16);
}

// ---------------------------------------------------------------------------
// GEMM: C[z][m][n] = scale * sum_k A[z][m][k] * Bt[z][n][k]  (+ bias[n])
// ATY/BTY: 0 = f32 source (convert to bf16), 1 = bf16 source.
// CTY: 0 f32, 2 bf16,
//      4 split: col<csplit -> bf16 to Cp; col>=csplit -> bf16 TRANSPOSED to Cp2
//        as VT[b][col-csplit][row&1023] (strides 524288/1024, batch=row>>10),
//      5 KV-EMA: master(Cp,f32,RMW) = 0.9*master + 0.1*(acc*scale+bias);
//        col<csplit -> bf16(master) to Cp3 (stride 512); else transposed to Cp2.
// Double-buffered BK=64, register-prefetch staging. Kdim % 64 == 0.
// ---------------------------------------------------------------------------
template<int BM, int BN, int ATY, int BTY, int CTY, bool GUARD, bool BIAS>
__global__ __launch_bounds__(256) void gemm2(
    const void* __restrict__ Ap, long long Asb, long long Ash, int Ars,
    const void* __restrict__ Bp, long long Bsb, long long Bsh, int Brs,
    void* __restrict__ Cp, long long Csb, long long Csh, int Crs,
    void* __restrict__ Cp2, int csplit, void* __restrict__ Cp3,
    const float* __restrict__ bias, float scale, int M, int Kdim, int Hh)
{
  constexpr int LDP = 72;                       // 64 + 8 pad
  constexpr int WN = (BN >= 128) ? 2 : (BM >= 128 ? 1 : 2);
  constexpr int WM = 4 / WN;
  constexpr int MI = BM / (WM * 16);
  constexpr int NI = BN / (WN * 16);
  constexpr int AP = BM / 32;
  constexpr int BP = BN / 32;

  __shared__ unsigned short As[2][BM][LDP];
  __shared__ unsigned short Bs[2][BN][LDP];

  const int tid  = threadIdx.x;
  const int lane = tid & 63;
  const int w    = tid >> 6;
  const int wm   = w / WN, wn = w % WN;
  const int z    = blockIdx.z;
  const int zb   = z / Hh, zh = z - zb * Hh;
  const int m0   = blockIdx.x * BM;
  const int n0   = blockIdx.y * BN;
  const int lrow = lane & 15;
  const int lkB  = (lane >> 4) * 8;
  const int srow = tid >> 3;                    // 0..31
  const int scol = (tid & 7) * 8;               // 0..56

  const float*          Af  = (const float*)Ap          + zb * Asb + zh * Ash;
  const unsigned short* Ahp = (const unsigned short*)Ap + zb * Asb + zh * Ash;
  const float*          Bf  = (const float*)Bp          + zb * Bsb + zh * Bsh;
  const unsigned short* Bhp = (const unsigned short*)Bp + zb * Bsb + zh * Bsh;

  float4 afl[AP][2]; uint4 ahl[AP];
  float4 bfl[BP][2]; uint4 bhl[BP];

  auto loadT = [&](int k0) {
    #pragma unroll
    for (int p = 0; p < AP; ++p) {
      const int row = srow + p * 32;
      const bool ok = !GUARD || (m0 + row) < M;
      if constexpr (ATY == 0) {
        if (ok) {
          const float* s = Af + (long long)(m0 + row) * Ars + k0 + scol;
          afl[p][0] = *(const float4*)s;
          afl[p][1] = *(const float4*)(s + 4);
        } else {
          afl[p][0] = make_float4(0.f,0.f,0.f,0.f);
          afl[p][1] = make_float4(0.f,0.f,0.f,0.f);
        }
      } else {
        ahl[p] = ok ? *(const uint4*)(Ahp + (long long)(m0 + row) * Ars + k0 + scol)
                    : make_uint4(0u,0u,0u,0u);
      }
    }
    #pragma unroll
    for (int p = 0; p < BP; ++p) {
      const int row = srow + p * 32;
      if constexpr (BTY == 0) {
        const float* s = Bf + (long long)(n0 + row) * Brs + k0 + scol;
        bfl[p][0] = *(const float4*)s;
        bfl[p][1] = *(const float4*)(s + 4);
      } else {
        bhl[p] = *(const uint4*)(Bhp + (long long)(n0 + row) * Brs + k0 + scol);
      }
    }
  };
  auto writeT = [&](int buf) {
    #pragma unroll
    for (int p = 0; p < AP; ++p) {
      const int row = srow + p * 32;
      uint4 u;
      if constexpr (ATY == 0) {
        u.x = pk(afl[p][0].x, afl[p][0].y); u.y = pk(afl[p][0].z, afl[p][0].w);
        u.z = pk(afl[p][1].x, afl[p][1].y); u.w = pk(afl[p][1].z, afl[p][1].w);
      } else u = ahl[p];
      *(uint4*)(&As[buf][row][scol]) = u;
    }
    #pragma unroll
    for (int p = 0; p < BP; ++p) {
      const int row = srow + p * 32;
      uint4 u;
      if constexpr (BTY == 0) {
        u.x = pk(bfl[p][0].x, bfl[p][0].y); u.y = pk(bfl[p][0].z, bfl[p][0].w);
        u.z = pk(bfl[p][1].x, bfl[p][1].y); u.w = pk(bfl[p][1].z, bfl[p][1].w);
      } else u = bhl[p];
      *(uint4*)(&Bs[buf][row][scol]) = u;
    }
  };

  f32x4 acc[MI][NI] = {};

  loadT(0);
  writeT(0);
  __syncthreads();

  const int NT = Kdim >> 6;
  int cur = 0;
  for (int t = 0; t < NT; ++t) {
    const bool more = (t + 1) < NT;
    if (more) loadT((t + 1) << 6);

    short8 a8[MI][2], b8[NI][2];
    #pragma unroll
    for (int mi = 0; mi < MI; ++mi) {
      const unsigned short* r = &As[cur][wm * (MI * 16) + mi * 16 + lrow][lkB];
      a8[mi][0] = *(const short8*)r;
      a8[mi][1] = *(const short8*)(r + 32);
    }
    #pragma unroll
    for (int ni = 0; ni < NI; ++ni) {
      const unsigned short* r = &Bs[cur][wn * (NI * 16) + ni * 16 + lrow][lkB];
      b8[ni][0] = *(const short8*)r;
      b8[ni][1] = *(const short8*)(r + 32);
    }
    #pragma unroll
    for (int kk = 0; kk < 2; ++kk)
      #pragma unroll
      for (int mi = 0; mi < MI; ++mi)
        #pragma unroll
        for (int ni = 0; ni < NI; ++ni)
          acc[mi][ni] = __builtin_amdgcn_mfma_f32_16x16x32_bf16(a8[mi][kk], b8[ni][kk], acc[mi][ni], 0, 0, 0);

    if (more) writeT(cur ^ 1);
    __syncthreads();
    cur ^= 1;
  }

  // ---- epilogue: D[row][col], row=(lane>>4)*4+r, col=lane&15 ----
  float*          Cf  = (float*)Cp          + zb * Csb + zh * Csh;
  unsigned short* Chn = (unsigned short*)Cp + zb * Csb + zh * Csh;
  unsigned short* Ch2 = (unsigned short*)Cp2;
  unsigned short* Kb3 = (unsigned short*)Cp3;
  const bool trside = (CTY == 4 || CTY == 5) ? (n0 >= csplit) : false;

  #pragma unroll
  for (int ni = 0; ni < NI; ++ni) {
    const int col = n0 + wn * (NI * 16) + ni * 16 + lrow;
    const float bv = BIAS ? bias[col] : 0.0f;
    #pragma unroll
    for (int mi = 0; mi < MI; ++mi) {
      const int rbase = m0 + wm * (MI * 16) + mi * 16 + ((lane >> 4) << 2);
      if constexpr (CTY == 5) {
        ushort4 vt;
        #pragma unroll
        for (int r = 0; r < 4; ++r) {
          const int row = rbase + r;
          const float proj = acc[mi][ni][r] * scale + bv;
          const long long midx = (long long)row * Crs + col;
          const float v = 0.9f * Cf[midx] + 0.1f * proj;
          Cf[midx] = v;
          if (!trside) Kb3[(long long)row * 512 + col] = f32_bf16(v);
          else ((unsigned short*)&vt)[r] = f32_bf16(v);
        }
        if (trside)
          *(ushort4*)(&Ch2[(long long)(rbase >> 10) * 524288
                           + (long long)(col - csplit) * 1024 + (rbase & 1023)]) = vt;
      } else if (trside) {
        ushort4 v;
        v.x = f32_bf16(acc[mi][ni][0] * scale + bv);
        v.y = f32_bf16(acc[mi][ni][1] * scale + bv);
        v.z = f32_bf16(acc[mi][ni][2] * scale + bv);
        v.w = f32_bf16(acc[mi][ni][3] * scale + bv);
        *(ushort4*)(&Ch2[(long long)(rbase >> 10) * 524288
                         + (long long)(col - csplit) * 1024 + (rbase & 1023)]) = v;
      } else {
        #pragma unroll
        for (int r = 0; r < 4; ++r) {
          const int row = rbase + r;
          if (!GUARD || row < M) {
            const float v = acc[mi][ni][r] * scale + bv;
            if constexpr (CTY == 0)      Cf [(long long)row * Crs + col] = v;
            else                         Chn[(long long)row * Crs + col] = f32_bf16(v);
          }
        }
      }
    }
  }
}

// ---------------------------------------------------------------------------
// Flash MHA: per (b,h), q-tile 64 rows. QK bf16 [4][1024][q0..511|k512..1023],
// Vt bf16 [4][512][1024] (row=d, col=key). OH bf16 [4][1024][512].
// Online softmax, scale 1/8. 4 waves x 16 q-rows. Keys 1024 in 16 tiles of 64.
// ---------------------------------------------------------------------------
__global__ __launch_bounds__(256) void flash_mha(
    const unsigned short* __restrict__ QK, const unsigned short* __restrict__ Vt,
    unsigned short* __restrict__ OH)
{
  constexpr int LDP = 72;
  __shared__ unsigned short Qs[64][LDP];
  __shared__ unsigned short Ks[2][64][LDP];
  __shared__ unsigned short Vs[2][64][LDP];
  __shared__ unsigned short Ps[64][LDP];

  const int tid = threadIdx.x, lane = tid & 63, w = tid >> 6;
  const int z = blockIdx.y, b = z >> 3, h = z & 7;
  const int q0 = blockIdx.x * 64;
  const unsigned short* Qp = QK + (long long)b * 1048576 + h * 64;
  const unsigned short* Kp = Qp + 512;
  const unsigned short* Vp = Vt + (long long)b * 524288 + (long long)(h * 64) * 1024;
  unsigned short* Op = OH + (long long)b * 524288 + h * 64;

  const int srow = tid >> 3;        // 0..31
  const int scol = (tid & 7) * 8;   // 0..56

  #pragma unroll
  for (int p = 0; p < 2; ++p) {
    const int row = srow + p * 32;
    *(uint4*)(&Qs[row][scol]) = *(const uint4*)(Qp + (long long)(q0 + row) * 1024 + scol);
  }

  uint4 kl[2], vl[2];
  auto loadKV = [&](int kt) {
    #pragma unroll
    for (int p = 0; p < 2; ++p) {
      const int row = srow + p * 32;
      kl[p] = *(const uint4*)(Kp + (long long)(kt * 64 + row) * 1024 + scol);
      vl[p] = *(const uint4*)(Vp + (long long)row * 1024 + kt * 64 + scol);
    }
  };
  auto writeKV = [&](int buf) {
    #pragma unroll
    for (int p = 0; p < 2; ++p) {
      const int row = srow + p * 32;
      *(uint4*)(&Ks[buf][row][scol]) = kl[p];
      *(uint4*)(&Vs[buf][row][scol]) = vl[p];
    }
  };

  const int wq = w * 16;
  const int lr = lane & 15, lk = (lane >> 4) * 8;

  loadKV(0); writeKV(0);
  __syncthreads();

  short8 qa[2];
  qa[0] = *(const short8*)(&Qs[wq + lr][lk]);
  qa[1] = *(const short8*)(&Qs[wq + lr][32 + lk]);

  f32x4 acc[4] = {};
  f32x4 m4, l4;
  m4[0] = m4[1] = m4[2] = m4[3] = -1e30f;
  l4[0] = l4[1] = l4[2] = l4[3] = 0.f;

  int cur = 0;
  for (int kt = 0; kt < 16; ++kt) {
    const bool more = kt < 15;
    if (more) loadKV(kt + 1);

    f32x4 s[4] = {};
    #pragma unroll
    for (int ks = 0; ks < 2; ++ks)
      #pragma unroll
      for (int ni = 0; ni < 4; ++ni) {
        const short8 kb = *(const short8*)(&Ks[cur][ni * 16 + lr][ks * 32 + lk]);
        s[ni] = __builtin_amdgcn_mfma_f32_16x16x32_bf16(qa[ks], kb, s[ni], 0, 0, 0);
      }

    f32x4 rm;
    #pragma unroll
    for (int ni = 0; ni < 4; ++ni)
      #pragma unroll
      for (int r = 0; r < 4; ++r) s[ni][r] *= 0.125f;
    rm = s[0];
    #pragma unroll
    for (int ni = 1; ni < 4; ++ni)
      #pragma unroll
      for (int r = 0; r < 4; ++r) rm[r] = fmaxf(rm[r], s[ni][r]);
    #pragma unroll
    for (int d = 1; d < 16; d <<= 1)
      #pragma unroll
      for (int r = 0; r < 4; ++r) rm[r] = fmaxf(rm[r], __shfl_xor(rm[r], d));

    f32x4 al;
    #pragma unroll
    for (int r = 0; r < 4; ++r) {
      const float mn = fmaxf(m4[r], rm[r]);
      al[r] = __expf(m4[r] - mn);
      m4[r] = mn;
    }
    f32x4 ls; ls[0] = ls[1] = ls[2] = ls[3] = 0.f;
    #pragma unroll
    for (int ni = 0; ni < 4; ++ni)
      #pragma unroll
      for (int r = 0; r < 4; ++r) { s[ni][r] = __expf(s[ni][r] - m4[r]); ls[r] += s[ni][r]; }
    #pragma unroll
    for (int d = 1; d < 16; d <<= 1)
      #pragma unroll
      for (int r = 0; r < 4; ++r) ls[r] += __shfl_xor(ls[r], d);
    #pragma unroll
    for (int r = 0; r < 4; ++r) l4[r] = l4[r] * al[r] + ls[r];
    #pragma unroll
    for (int ni = 0; ni < 4; ++ni)
      #pragma unroll
      for (int r = 0; r < 4; ++r) acc[ni][r] *= al[r];

    // P -> Ps (wave-local 16-row slab; same-wave LDS ops are in order)
    const int prow = wq + ((lane >> 4) << 2);
    #pragma unroll
    for (int ni = 0; ni < 4; ++ni)
      #pragma unroll
      for (int r = 0; r < 4; ++r)
        Ps[prow + r][ni * 16 + lr] = f32_bf16(s[ni][r]);

    #pragma unroll
    for (int ks = 0; ks < 2; ++ks) {
      const short8 pa = *(const short8*)(&Ps[wq + lr][ks * 32 + lk]);
      #pragma unroll
      for (int nd = 0; nd < 4; ++nd) {
        const short8 vb = *(const short8*)(&Vs[cur][nd * 16 + lr][ks * 32 + lk]);
        acc[nd] = __builtin_amdgcn_mfma_f32_16x16x32_bf16(pa, vb, acc[nd], 0, 0, 0);
      }
    }
    if (more) writeKV(cur ^ 1);
    __syncthreads();
    cur ^= 1;
  }

  const int orow = q0 + wq + ((lane >> 4) << 2);
  #pragma unroll
  for (int nd = 0; nd < 4; ++nd)
    #pragma unroll
    for (int r = 0; r < 4; ++r)
      Op[(long long)(orow + r) * 512 + nd * 16 + lr] = f32_bf16(acc[nd][r] / l4[r]);
}

// ---------------------------------------------------------------------------
__global__ __launch_bounds__(256) void transpose_f32_bf16(
    const float* __restrict__ in, unsigned short* __restrict__ out, int R, int C)
{
  __shared__ float tile[32][33];
  const int c0 = blockIdx.x * 32, r0 = blockIdx.y * 32;
  const int xx = threadIdx.x & 31, ys = threadIdx.x >> 5;
  #pragma unroll
  for (int yy = ys; yy < 32; yy += 8)
    tile[yy][xx] = in[(long long)(r0 + yy) * C + c0 + xx];
  __syncthreads();
  #pragma unroll
  for (int yy = ys; yy < 32; yy += 8)
    out[(long long)(c0 + yy) * R + r0 + xx] = f32_bf16(tile[xx][yy]);
}

// ---------------------------------------------------------------------------
// Row softmax, row length 1024, one wave per row. f32 in -> bf16 out (obuf).
// ---------------------------------------------------------------------------
__global__ __launch_bounds__(256) void softmax_rows_bf(
    const float* __restrict__ buf, unsigned short* __restrict__ obuf,
    int rowsPerZ, long long zStride)
{
  const int gr   = blockIdx.x * 4 + (threadIdx.x >> 6);
  const int lane = threadIdx.x & 63;
  const int z = gr / rowsPerZ;
  const int i = gr - z * rowsPerZ;
  const float* pf = buf + (long long)z * zStride + (long long)i * 1024 + lane * 16;
  float v[16];
  #pragma unroll
  for (int j = 0; j < 4; ++j) {
    const float4 f = ((const float4*)pf)[j];
    v[4*j+0] = f.x; v[4*j+1] = f.y; v[4*j+2] = f.z; v[4*j+3] = f.w;
  }
  float mx = v[0];
  #pragma unroll
  for (int j = 1; j < 16; ++j) mx = fmaxf(mx, v[j]);
  #pragma unroll
  for (int d = 32; d; d >>= 1) mx = fmaxf(mx, __shfl_xor(mx, d));
  float s = 0.0f;
  #pragma unroll
  for (int j = 0; j < 16; ++j) { v[j] = __expf(v[j] - mx); s += v[j]; }
  #pragma unroll
  for (int d = 32; d; d >>= 1) s += __shfl_xor(s, d);
  const float inv = 1.0f / s;
  unsigned short* ph = obuf + (long long)z * zStride + (long long)i * 1024 + lane * 16;
  unsigned uu[8];
  #pragma unroll
  for (int j = 0; j < 8; ++j) uu[j] = pk(v[2*j] * inv, v[2*j+1] * inv);
  ((uint4*)ph)[0] = make_uint4(uu[0], uu[1], uu[2], uu[3]);
  ((uint4*)ph)[1] = make_uint4(uu[4], uu[5], uu[6], uu[7]);
}

// --------------------------- elementwise helpers ---------------------------
__global__ __launch_bounds__(256) void copy_pm_bf(const float* __restrict__ pm, unsigned short* __restrict__ comb)
{
  const int idx = blockIdx.x * 256 + threadIdx.x;   // 8192
  const int b = idx >> 11, e = idx & 2047;
  const int row = e >> 6, d8 = (e & 63) * 8;
  const float* s = pm + row * 512 + d8;
  const float4 f0 = *(const float4*)s;
  const float4 f1 = *(const float4*)(s + 4);
  uint4 u; u.x = pk(f0.x, f0.y); u.y = pk(f0.z, f0.w); u.z = pk(f1.x, f1.y); u.w = pk(f1.z, f1.w);
  *(uint4*)(comb + (long long)b * 524288 + row * 512 + d8) = u;
}

__global__ __launch_bounds__(256) void copy_chunk_bf(const float* __restrict__ x, unsigned short* __restrict__ comb, int ci)
{
  const int idx = blockIdx.x * 256 + threadIdx.x;   // 126976
  const int b = idx / 31744, e = idx % 31744;
  const int row = e >> 6, d8 = (e & 63) * 8;
  const float* s = x + ((long long)b * 3968 + ci * 496 + row) * 512 + d8;
  const float4 f0 = *(const float4*)s;
  const float4 f1 = *(const float4*)(s + 4);
  uint4 u; u.x = pk(f0.x, f0.y); u.y = pk(f0.z, f0.w); u.z = pk(f1.x, f1.y); u.w = pk(f1.z, f1.w);
  *(uint4*)(comb + (long long)b * 524288 + (528 + row) * 512 + d8) = u;
}

__global__ __launch_bounds__(256) void init_kv(const float* __restrict__ mkb, const float* __restrict__ mvb,
                                               float* __restrict__ master, unsigned short* __restrict__ Kb)
{
  const int idx = blockIdx.x * 256 + threadIdx.x;   // 1M : [4096 rows][256 col4]
  const int c4 = (idx & 255) * 4;
  const long long row = idx >> 8;
  const float4 v = *(const float4*)((c4 < 512) ? (mkb + c4) : (mvb + c4 - 512));
  *(float4*)(master + row * 1024 + c4) = v;
  if (c4 < 512) {
    ushort4 h; h.x = f32_bf16(v.x); h.y = f32_bf16(v.y); h.z = f32_bf16(v.z); h.w = f32_bf16(v.w);
    *(ushort4*)(Kb + row * 512 + c4) = h;
  }
}

__global__ __launch_bounds__(256) void init_vt(const float* __restrict__ mvb, unsigned short* __restrict__ VT)
{
  const int idx = blockIdx.x * 256 + threadIdx.x;   // 262144 : [4][512][128 k8]
  const int k8 = (idx & 127) * 8;
  const int d  = (idx >> 7) & 511;
  const int b  = idx >> 16;
  const unsigned short hv = f32_bf16(mvb[d]);
  const ushort4 h4 = make_ushort4(hv, hv, hv, hv);
  unsigned short* dst = VT + (long long)b * 524288 + (long long)d * 1024 + k8;
  *(ushort4*)dst = h4; *(ushort4*)(dst + 4) = h4;
}

__global__ __launch_bounds__(256) void fuse_bias(const float* __restrict__ bq, const float* __restrict__ mq,
                                                 const float* __restrict__ mqb, float* __restrict__ bqm)
{
  const int c = blockIdx.x * 256 + threadIdx.x;     // 512
  float s = mqb[c];
  for (int j = 0; j < 512; ++j) s += bq[j] * mq[j * 512 + c];
  bqm[c] = s;
}

__global__ __launch_bounds__(256) void outmul_k(const float4* __restrict__ att, const float4* __restrict__ mo,
                                                float4* __restrict__ out, int ci)
{
  const int idx = blockIdx.x * 256 + threadIdx.x;   // 253952
  const int b = idx / 63488, rem = idx % 63488;
  const int r = rem >> 7, d = rem & 127;
  const float4 a = att[(long long)((b << 10) + 528 + r) * 128 + d];
  const float4 m = mo[(long long)(b * 496 + r) * 128 + d];
  float4 o;
  o.x = a.x*m.x; o.y = a.y*m.y; o.z = a.z*m.z; o.w = a.w*m.w;
  out[(long long)(b * 3968 + ci * 496 + r) * 128 + d] = o;
}

// ---------------------------------------------------------------------------
extern "C" void kernel_launch(void* const* d_in, const int* in_sizes, int n_in,
                              void* d_out, int out_size, void* d_ws, size_t ws_size,
                              hipStream_t stream)
{
  (void)in_sizes; (void)n_in; (void)out_size; (void)ws_size;
  const float* x   = (const float*)d_in[0];
  const float* pm  = (const float*)d_in[1];
  const float* Wq  = (const float*)d_in[2];
  const float* bq  = (const float*)d_in[3];
  const float* mkw = (const float*)d_in[4];
  const float* mkb = (const float*)d_in[5];
  const float* mvw = (const float*)d_in[6];
  const float* mvb = (const float*)d_in[7];
  const float* mqw = (const float*)d_in[8];
  const float* mqb = (const float*)d_in[9];
  const float* aqw = (const float*)d_in[10];
  const float* aqb = (const float*)d_in[11];
  const float* akw = (const float*)d_in[12];
  const float* akb = (const float*)d_in[13];
  const float* avw = (const float*)d_in[14];
  const float* avb = (const float*)d_in[15];
  const float* aow = (const float*)d_in[16];
  const float* aob = (const float*)d_in[17];
  float* out = (float*)d_out;

  char* wsp = (char*)d_ws;
  size_t off = 0;
  auto alloc = [&](size_t b) -> void* { void* p = wsp + off; off += (b + 255) & ~(size_t)255; return p; };

  unsigned short* WTmq = (unsigned short*)alloc(524288);   // mq^T bf16 [512][512]
  unsigned short* WKV  = (unsigned short*)alloc(1048576);  // [mk;mv]^T [1024][512]
  unsigned short* WQKV = (unsigned short*)alloc(1572864);  // [aq;ak;av]^T [1536][512]
  unsigned short* WTao = (unsigned short*)alloc(524288);   // ao^T
  unsigned short* Wqm  = (unsigned short*)alloc(524288);   // (Wq@mq)^T bf16 [512][512]
  float* bkv  = (float*)alloc(4096);
  float* bqkv = (float*)alloc(6144);
  float* bqm  = (float*)alloc(2048);
  float*          master = (float*)alloc(16777216);        // f32 [4,1024,1024] = EMA'd [K|V]
  unsigned short* Kb   = (unsigned short*)alloc(4194304);  // bf16 [4,1024,512]
  unsigned short* VT   = (unsigned short*)alloc(4194304);  // bf16 [4,512,1024] (retrieve V^T)
  unsigned short* VTm  = (unsigned short*)alloc(4194304);  // bf16 [4,512,1024] (MHA V^T)
  unsigned short* QP   = (unsigned short*)alloc(2031616);  // bf16 [4,496,512]
  unsigned short* comb = (unsigned short*)alloc(4194304);  // bf16 [4,1024,512]
  unsigned short* QKb  = (unsigned short*)alloc(8388608);  // bf16 [4,1024,1024] (q|k)
  unsigned short* OH   = (unsigned short*)alloc(4194304);  // bf16 [4,1024,512]
  float*          ATT  = (float*)alloc(8388608);           // f32 [4,1024,512]
  float*          OH2  = (float*)alloc(4063232);           // f32 [4,496,512]
  float*          SC   = (float*)alloc(8126464);           // f32 [4,496,1024]
  unsigned short* SCb  = (unsigned short*)alloc(4063232);  // bf16 [4,496,1024]

  const long long XBS = 2031616, BS = 524288, QBS = 253952;
  const long long SCB = 507904;                 // 496*1024
  const float sr = 0.044194173824159216f;       // 1/sqrt(512)

  // -------- prep (once per call) --------
  transpose_f32_bf16<<<dim3(16,16,1),256,0,stream>>>(mqw, WTmq,          512, 512);
  transpose_f32_bf16<<<dim3(16,16,1),256,0,stream>>>(mkw, WKV,           512, 512);
  transpose_f32_bf16<<<dim3(16,16,1),256,0,stream>>>(mvw, WKV  + 262144, 512, 512);
  transpose_f32_bf16<<<dim3(16,16,1),256,0,stream>>>(aqw, WQKV,          512, 512);
  transpose_f32_bf16<<<dim3(16,16,1),256,0,stream>>>(akw, WQKV + 262144, 512, 512);
  transpose_f32_bf16<<<dim3(16,16,1),256,0,stream>>>(avw, WQKV + 524288, 512, 512);
  transpose_f32_bf16<<<dim3(16,16,1),256,0,stream>>>(aow, WTao,          512, 512);
  // Wqm[n][k] = sum_j mq^T[n][j] * Wq[k][j]  = (Wq@mq)^T
  gemm2<64,64,1,0,2,false,false><<<dim3(8,8,1),256,0,stream>>>(
    WTmq, 0, 0, 512, Wq, 0, 0, 512, Wqm, 0, 0, 512,
    nullptr, 0, nullptr, nullptr, 1.0f, 512, 512, 1);
  fuse_bias<<<2,256,0,stream>>>(bq, mqw, mqb, bqm);
  hipMemcpyAsync(bkv,        mkb, 2048, hipMemcpyDeviceToDevice, stream);
  hipMemcpyAsync(bkv  + 512, mvb, 2048, hipMemcpyDeviceToDevice, stream);
  hipMemcpyAsync(bqkv,       aqb, 2048, hipMemcpyDeviceToDevice, stream);
  hipMemcpyAsync(bqkv + 512, akb, 2048, hipMemcpyDeviceToDevice, stream);
  hipMemcpyAsync(bqkv +1024, avb, 2048, hipMemcpyDeviceToDevice, stream);
  init_kv<<<4096,256,0,stream>>>(mkb, mvb, master, Kb);
  init_vt<<<1024,256,0,stream>>>(mvb, VT);
  copy_pm_bf<<<32,256,0,stream>>>(pm, comb);

  for (int ci = 0; ci < 8; ++ci) {
    copy_chunk_bf<<<496,256,0,stream>>>(x, comb, ci);

    // qp1 = chunk @ (Wq@mq) + bqm -> QP bf16
    gemm2<64,64,0,1,2,true,true><<<dim3(8,8,4),256,0,stream>>>(
      x + (long long)ci * 253952, XBS, 0, 512, Wqm, 0, 0, 512,
      QP, QBS, 0, 512, nullptr, 0, nullptr, bqm, 1.0f, 496, 512, 1);
    // scores1 = qp @ K^T / sqrt(D)
    gemm2<64,64,1,1,0,true,false><<<dim3(8,16,4),256,0,stream>>>(
      QP, QBS, 0, 512, Kb, BS, 0, 512,
      SC, SCB, 0, 1024, nullptr, 0, nullptr, nullptr, sr, 496, 512, 1);
    softmax_rows_bf<<<496,256,0,stream>>>(SC, SCb, 496, SCB);
    // hist = probs @ V -> comb rows 32..527
    gemm2<64,64,1,1,2,true,false><<<dim3(8,8,4),256,0,stream>>>(
      SCb, SCB, 0, 1024, VT, BS, 0, 1024,
      comb + 32 * 512, BS, 0, 512, nullptr, 0, nullptr, nullptr, 1.0f, 496, 1024, 1);

    // MHA qkv: comb @ [aq|ak|av]; q|k -> QKb, v -> VTm transposed
    gemm2<128,64,1,1,4,false,true><<<dim3(32,24,1),256,0,stream>>>(
      comb, 0, 0, 512, WQKV, 0, 0, 512,
      QKb, 0, 0, 1024, VTm, 1024, nullptr, bqkv, 1.0f, 4096, 512, 1);
    flash_mha<<<dim3(16,32,1),256,0,stream>>>(QKb, VTm, OH);
    // attended = OH @ ao + aob -> ATT f32
    gemm2<128,64,1,1,0,false,true><<<dim3(32,8,1),256,0,stream>>>(
      OH, 0, 0, 512, WTao, 0, 0, 512,
      ATT, 0, 0, 512, nullptr, 0, nullptr, aob, 1.0f, 4096, 512, 1);

    // KV-EMA: master = 0.9*master + 0.1*(ATT @ [mk|mv] + b); emit Kb bf16 + VT^T bf16
    gemm2<128,64,0,1,5,false,true><<<dim3(32,16,1),256,0,stream>>>(
      ATT, 0, 0, 512, WKV, 0, 0, 512,
      master, 0, 0, 1024, VT, 512, Kb, bkv, 1.0f, 4096, 512, 1);

    // retrieve2 (last 496 rows): qp2 = ATT[:,528:] @ mq + mqb
    gemm2<64,64,0,1,2,true,true><<<dim3(8,8,4),256,0,stream>>>(
      ATT + 528 * 512, BS, 0, 512, WTmq, 0, 0, 512,
      QP, QBS, 0, 512, nullptr, 0, nullptr, mqb, 1.0f, 496, 512, 1);
    gemm2<64,64,1,1,0,true,false><<<dim3(8,16,4),256,0,stream>>>(
      QP, QBS, 0, 512, Kb, BS, 0, 512,
      SC, SCB, 0, 1024, nullptr, 0, nullptr, nullptr, sr, 496, 512, 1);
    softmax_rows_bf<<<496,256,0,stream>>>(SC, SCb, 496, SCB);
    gemm2<64,64,1,1,0,true,false><<<dim3(8,8,4),256,0,stream>>>(
      SCb, SCB, 0, 1024, VT, BS, 0, 1024,
      OH2, QBS, 0, 512, nullptr, 0, nullptr, nullptr, 1.0f, 496, 1024, 1);

    outmul_k<<<992,256,0,stream>>>((const float4*)ATT, (const float4*)OH2, (float4*)out, ci);
  }
}